// Round 4
// baseline (3550.531 us; speedup 1.0000x reference)
//
#include <hip/hip_runtime.h>

// Problem constants (from reference): T=8, D=512, H=100, C=2, NEG=1
constexpr int D_ = 512;
constexpr int H_ = 100;
constexpr int C_ = 2;
constexpr int T_ = 8;

constexpr int TE = 128;         // edges per block in main kernel
constexpr int DC = 32;          // D-chunk (floats) staged in LDS = one 128B line/row
constexpr int NC = D_ / DC;     // 16 chunks
constexpr int NTH = 1024;       // threads per main block (16 waves -> 4/SIMD)
constexpr int SB = 128;         // sort segments / blocks
constexpr int STH = 256;        // threads per sort block

// ws layout (ints): [0:8) typeBase | [8:16) typeCount | [16:25) tileBase
//                   [32:32+SB*8) hist/blockBase | [1056 : 1056+E) sorted_e
constexpr int WS_HIST = 32;
constexpr int WS_SORTED = 32 + SB * T_;   // 1056

// ---------------------------------------------------------------------------
// K1: per-segment histogram. SB blocks x STH threads.
// ---------------------------------------------------------------------------
__global__ __launch_bounds__(STH) void k_hist(const int* __restrict__ et, int E, int seg,
                                              int* __restrict__ hist) {
    __shared__ int hb[T_];
    const int b = blockIdx.x, tid = threadIdx.x;
    if (tid < T_) hb[tid] = 0;
    __syncthreads();
    const int segLo = b * seg;
    const int segHi = min(E, segLo + seg);
    const int per = (seg + STH - 1) / STH;
    const int lo = segLo + tid * per;
    const int hi = min(segHi, lo + per);
    int c[T_];
#pragma unroll
    for (int j = 0; j < T_; ++j) c[j] = 0;
    for (int i = lo; i < hi; ++i) {
        int ty = et[i];
#pragma unroll
        for (int j = 0; j < T_; ++j) c[j] += (ty == j) ? 1 : 0;
    }
#pragma unroll
    for (int j = 0; j < T_; ++j)
        if (c[j]) atomicAdd(&hb[j], c[j]);
    __syncthreads();
    if (tid < T_) hist[b * T_ + tid] = hb[tid];
}

// ---------------------------------------------------------------------------
// K2: scan over SB segment histograms (one block of SB threads).
// Produces typeBase/typeCount/tileBase and rewrites hist -> blockBase[b][t].
// ---------------------------------------------------------------------------
__global__ __launch_bounds__(SB) void k_scan(int* __restrict__ hist,
                                             int* __restrict__ typeBase,
                                             int* __restrict__ typeCount,
                                             int* __restrict__ tileBase) {
    __shared__ int sc[SB][T_ + 1];   // stride 9 -> conflict-free
    __shared__ int sbase[T_];
    const int tid = threadIdx.x;
#pragma unroll
    for (int j = 0; j < T_; ++j) sc[tid][j] = hist[tid * T_ + j];
    __syncthreads();
    for (int ofs = 1; ofs < SB; ofs <<= 1) {
        int v[T_];
        if (tid >= ofs) {
#pragma unroll
            for (int j = 0; j < T_; ++j) v[j] = sc[tid - ofs][j];
        }
        __syncthreads();
        if (tid >= ofs) {
#pragma unroll
            for (int j = 0; j < T_; ++j) sc[tid][j] += v[j];
        }
        __syncthreads();
    }
    if (tid == 0) {
        int b = 0, tb = 0;
#pragma unroll
        for (int j = 0; j < T_; ++j) {
            int cntj = sc[SB - 1][j];
            sbase[j] = b;
            typeBase[j] = b;
            typeCount[j] = cntj;
            tileBase[j] = tb;
            b += cntj;
            tb += (cntj + TE - 1) / TE;
        }
        tileBase[T_] = tb;
    }
    __syncthreads();
#pragma unroll
    for (int j = 0; j < T_; ++j)
        hist[tid * T_ + j] = sbase[j] + (tid ? sc[tid - 1][j] : 0);
}

// ---------------------------------------------------------------------------
// K3: stable scatter. SB blocks x STH threads, same segmentation as K1.
// ---------------------------------------------------------------------------
__global__ __launch_bounds__(STH) void k_scatter(const int* __restrict__ et, int E, int seg,
                                                 const int* __restrict__ blockBase,
                                                 int* __restrict__ sorted_e) {
    __shared__ int sc[STH][T_ + 1];
    const int b = blockIdx.x, tid = threadIdx.x;
    const int segLo = b * seg;
    const int segHi = min(E, segLo + seg);
    const int per = (seg + STH - 1) / STH;
    const int lo = segLo + tid * per;
    const int hi = min(segHi, lo + per);
    int c[T_];
#pragma unroll
    for (int j = 0; j < T_; ++j) c[j] = 0;
    for (int i = lo; i < hi; ++i) {
        int ty = et[i];
#pragma unroll
        for (int j = 0; j < T_; ++j) c[j] += (ty == j) ? 1 : 0;
    }
#pragma unroll
    for (int j = 0; j < T_; ++j) sc[tid][j] = c[j];
    __syncthreads();
    for (int ofs = 1; ofs < STH; ofs <<= 1) {
        int v[T_];
        if (tid >= ofs) {
#pragma unroll
            for (int j = 0; j < T_; ++j) v[j] = sc[tid - ofs][j];
        }
        __syncthreads();
        if (tid >= ofs) {
#pragma unroll
            for (int j = 0; j < T_; ++j) sc[tid][j] += v[j];
        }
        __syncthreads();
    }
    int p[T_];
#pragma unroll
    for (int j = 0; j < T_; ++j)
        p[j] = blockBase[b * T_ + j] + (tid ? sc[tid - 1][j] : 0);
    for (int i = lo; i < hi; ++i) {
        int ty = et[i];
        int r = 0;
#pragma unroll
        for (int j = 0; j < T_; ++j) {
            if (ty == j) { r = p[j]; p[j] = r + 1; }
        }
        sorted_e[r] = i;
    }
}

// ---------------------------------------------------------------------------
// Main fused kernel, v4: 1024 threads (16 waves -> 4/SIMD TLP) with 96 KB
// LDS double buffer, which forces exactly ONE resident block per CU — the
// only regime measured to give logical HBM traffic (R1 vs R2/R3 A/B).
// TE=128, DC=32: each (row, chunk) is exactly one 128B line for staged
// loads and fused h_save stores. Out-layer in registers via 16-lane
// butterfly reduce.
// ---------------------------------------------------------------------------
__global__ __launch_bounds__(NTH, 4) void k_main(
    const float* __restrict__ h,
    const float* __restrict__ srcW, const float* __restrict__ srcB,
    const float* __restrict__ dstW, const float* __restrict__ dstB,
    const float* __restrict__ outW, const float* __restrict__ outB,
    const int* __restrict__ sorted_e,
    const int* __restrict__ typeBase, const int* __restrict__ typeCount,
    const int* __restrict__ tileBase,
    float* __restrict__ out, int E)
{
    const int b = blockIdx.x;
    if (b >= tileBase[T_]) return;
    int t = 0;
#pragma unroll
    for (int j = 1; j < T_; ++j) t += (b >= tileBase[j]) ? 1 : 0;
    const int i0   = (b - tileBase[t]) * TE;
    const int cnt  = typeCount[t];
    const int base = typeBase[t];
    const int tid = threadIdx.x;
    const int tx  = tid & 15;
    const int ty  = tid >> 4;          // 0..63

    // stage: [buf][m*1024 + r*8 + s8] float4; LDS slot s8 of row r holds
    // global f4-column s8 ^ (r&7) (XOR within the 128B row line).
    __shared__ __align__(16) float4 stg[2][3 * TE * (DC / 4)];   // 98304 B
    __shared__ int eIdx[TE];

    if (tid < TE) {
        int p = i0 + tid;
        eIdx[tid] = sorted_e[base + (p < cnt ? p : i0)];  // clamp pads to valid edge
    }
    __syncthreads();

    const int r   = tid >> 3;                 // staged row (edge slot) 0..127
    const int s8  = tid & 7;                  // f4 slot within row
    const int c4  = s8 ^ (r & 7);             // swizzled global f4-column
    const bool g  = (i0 + r) < cnt;
    const float* gsrc[3];
#pragma unroll
    for (int m = 0; m < 3; ++m)
        gsrc[m] = h + ((size_t)m * E + eIdx[r]) * D_ + (c4 << 2);

    float* const outH = out + (size_t)4 * E;        // h_save region
    const ptrdiff_t hsOfs = outH - h;               // uniform offset h -> h_save

    float4* const st0 = &stg[0][0];
    float4* const st1 = &stg[1][0];

    auto stage_issue = [&](float4* dstF4, int d0c) {
#pragma unroll
        for (int m = 0; m < 3; ++m) {
            __builtin_amdgcn_global_load_lds(
                (const __attribute__((address_space(1))) void*)(gsrc[m] + d0c),
                (__attribute__((address_space(3))) void*)(dstF4 + m * NTH + tid),
                16, 0, 0);
        }
    };

    float accS[2][7], accP[2][7], accN[2][7];
#pragma unroll
    for (int kk = 0; kk < 2; ++kk)
#pragma unroll
        for (int jj = 0; jj < 7; ++jj) { accS[kk][jj] = 0.f; accP[kk][jj] = 0.f; accN[kk][jj] = 0.f; }

    int jcs[7];
#pragma unroll
    for (int jj = 0; jj < 7; ++jj) {
        int j = jj * 16 + tx;
        jcs[jj] = (j < H_) ? j : (H_ - 1);   // clamp; clamped result zeroed later
    }

    int rowB[2], swk[2];
#pragma unroll
    for (int kk = 0; kk < 2; ++kk) {
        int rr = ty * 2 + kk;                // this thread's compute rows 0..127
        rowB[kk] = rr * 8;
        swk[kk]  = rr & 7;
    }

    const float* wsBase = srcW + (size_t)t * D_ * H_;
    const float* wdBase = dstW + (size_t)t * D_ * H_;

    stage_issue(st0, 0);   // prologue: chunk 0

#pragma unroll 1
    for (int ch = 0; ch < NC; ++ch) {
        const int d0 = ch * DC;
        float4* const cs = (ch & 1) ? st1 : st0;
        float4* const ns = (ch & 1) ? st0 : st1;

        __syncthreads();   // chunk-ch staging complete (issued one chunk ago)

        if (ch + 1 < NC) stage_issue(ns, d0 + DC);

        // fused h_save: read own linear slots (conflict-free), mirror-store
        // a full 128B line per 8-lane group
#pragma unroll
        for (int m = 0; m < 2; ++m) {
            float4 v = cs[m * NTH + tid];
            if (g) *(float4*)(const_cast<float*>(gsrc[m]) + hsOfs + d0) = v;
        }

        const float* pws = wsBase + (size_t)d0 * H_;
        const float* pwd = wdBase + (size_t)d0 * H_;
#pragma unroll
        for (int dd4 = 0; dd4 < DC / 4; ++dd4) {
            float4 Av[3][2];
#pragma unroll
            for (int m = 0; m < 3; ++m)
#pragma unroll
                for (int kk = 0; kk < 2; ++kk)
                    Av[m][kk] = cs[m * NTH + rowB[kk] + (dd4 ^ swk[kk])];
#pragma unroll
            for (int q = 0; q < 4; ++q) {
                const int d = dd4 * 4 + q;
                float wsv[7], wdv[7];
#pragma unroll
                for (int jj = 0; jj < 7; ++jj) {
                    wsv[jj] = pws[d * H_ + jcs[jj]];
                    wdv[jj] = pwd[d * H_ + jcs[jj]];
                }
#pragma unroll
                for (int kk = 0; kk < 2; ++kk) {
                    float as = ((const float*)&Av[0][kk])[q];
                    float ap = ((const float*)&Av[1][kk])[q];
                    float an = ((const float*)&Av[2][kk])[q];
#pragma unroll
                    for (int jj = 0; jj < 7; ++jj) {
                        accS[kk][jj] = fmaf(as, wsv[jj], accS[kk][jj]);
                        accP[kk][jj] = fmaf(ap, wdv[jj], accP[kk][jj]);
                        accN[kk][jj] = fmaf(an, wdv[jj], accN[kk][jj]);
                    }
                }
            }
        }
    }

    // ---- epilogue: bias + relu + out-layer, all in registers ----
    float sb[7], db[7], woA[7], woB[7];
#pragma unroll
    for (int jj = 0; jj < 7; ++jj) {
        sb[jj] = srcB[t * H_ + jcs[jj]];
        db[jj] = dstB[t * H_ + jcs[jj]];
        float2 wo = *(const float2*)(outW + (size_t)t * H_ * C_ + jcs[jj] * C_);
        woA[jj] = wo.x; woB[jj] = wo.y;
    }

    float part[8];   // part[kk*4 + pn*2 + c]
#pragma unroll
    for (int i = 0; i < 8; ++i) part[i] = 0.f;
#pragma unroll
    for (int kk = 0; kk < 2; ++kk) {
#pragma unroll
        for (int jj = 0; jj < 7; ++jj) {
            float s_ = accS[kk][jj] + sb[jj];
            float pe = fmaxf(s_ + accP[kk][jj] + db[jj], 0.f);
            float ne = fmaxf(s_ + accN[kk][jj] + db[jj], 0.f);
            if (jj == 6) {                    // zero clamped duplicate columns
                bool valid = (tx < 4);
                pe = valid ? pe : 0.f;
                ne = valid ? ne : 0.f;
            }
            part[kk * 4 + 0] = fmaf(pe, woA[jj], part[kk * 4 + 0]);
            part[kk * 4 + 1] = fmaf(pe, woB[jj], part[kk * 4 + 1]);
            part[kk * 4 + 2] = fmaf(ne, woA[jj], part[kk * 4 + 2]);
            part[kk * 4 + 3] = fmaf(ne, woB[jj], part[kk * 4 + 3]);
        }
    }

    // 16-lane butterfly: selector bits (c, pn, kk) from tx; lanes tx and tx+8
    // end duplicated -> guard tx<8.
    float v4[4];
#pragma unroll
    for (int a = 0; a < 4; ++a) {
        float keep = (tx & 1) ? part[2 * a + 1] : part[2 * a];
        float send = (tx & 1) ? part[2 * a] : part[2 * a + 1];
        v4[a] = keep + __shfl_xor(send, 1);
    }
    float v2_[2];
#pragma unroll
    for (int a = 0; a < 2; ++a) {
        float keep = (tx & 2) ? v4[2 * a + 1] : v4[2 * a];
        float send = (tx & 2) ? v4[2 * a] : v4[2 * a + 1];
        v2_[a] = keep + __shfl_xor(send, 2);
    }
    {
        float keep = (tx & 4) ? v2_[1] : v2_[0];
        float send = (tx & 4) ? v2_[0] : v2_[1];
        float v1 = keep + __shfl_xor(send, 4);
        float tot = v1 + __shfl_xor(v1, 8);

        const int c   = tx & 1;
        const int pn  = (tx >> 1) & 1;
        const int kkO = (tx >> 2) & 1;
        const int k   = ty * 2 + kkO;
        if (tx < 8 && (i0 + k) < cnt) {
            float val = tot + outB[t * C_ + c];
            size_t pidx = (size_t)(base + i0 + k) * C_ + c;
            out[(pn ? (size_t)C_ * E : (size_t)0) + pidx] = val;
        }
    }
}

// ---------------------------------------------------------------------------
extern "C" void kernel_launch(void* const* d_in, const int* in_sizes, int n_in,
                              void* d_out, int out_size, void* d_ws, size_t ws_size,
                              hipStream_t stream) {
    (void)n_in; (void)out_size; (void)ws_size;
    const float* h    = (const float*)d_in[0];
    const float* srcW = (const float*)d_in[1];
    const float* srcB = (const float*)d_in[2];
    const float* dstW = (const float*)d_in[3];
    const float* dstB = (const float*)d_in[4];
    const float* outW = (const float*)d_in[5];
    const float* outB = (const float*)d_in[6];
    const int*   et   = (const int*)d_in[7];
    const int E = in_sizes[7];

    float* out = (float*)d_out;
    int* ws = (int*)d_ws;
    int* typeBase  = ws;
    int* typeCount = ws + 8;
    int* tileBase  = ws + 16;
    int* hist      = ws + WS_HIST;
    int* sorted_e  = ws + WS_SORTED;

    const int seg = (E + SB - 1) / SB;
    k_hist<<<SB, STH, 0, stream>>>(et, E, seg, hist);
    k_scan<<<1, SB, 0, stream>>>(hist, typeBase, typeCount, tileBase);
    k_scatter<<<SB, STH, 0, stream>>>(et, E, seg, hist, sorted_e);

    const int maxTiles = (E + TE - 1) / TE + T_;   // >= sum of per-type ceil tiles
    k_main<<<maxTiles, NTH, 0, stream>>>(h, srcW, srcB, dstW, dstB, outW, outB,
                                         sorted_e, typeBase, typeCount, tileBase,
                                         out, E);
}

// Round 5
// 3539.301 us; speedup vs baseline: 1.0032x; 1.0032x over previous
//
#include <hip/hip_runtime.h>

// Problem constants (from reference): T=8, D=512, H=100, C=2, NEG=1
constexpr int D_ = 512;
constexpr int H_ = 100;
constexpr int C_ = 2;
constexpr int T_ = 8;

constexpr int TE = 128;         // edges per block in main kernel
constexpr int DC = 32;          // D-chunk (floats) staged in LDS = one 128B line/row
constexpr int NC = D_ / DC;     // 16 chunks
constexpr int NTH = 1024;       // threads per main block (16 waves -> 4/SIMD)
constexpr int SB = 128;         // sort segments / blocks
constexpr int STH = 256;        // threads per sort block

// ws layout (ints): [0:8) typeBase | [8:16) typeCount | [16:25) tileBase
//                   [32:32+SB*8) hist/blockBase | [1056 : 1056+E) sorted_e
constexpr int WS_HIST = 32;
constexpr int WS_SORTED = 32 + SB * T_;   // 1056

// ---------------------------------------------------------------------------
// K1: per-segment histogram. SB blocks x STH threads.
// ---------------------------------------------------------------------------
__global__ __launch_bounds__(STH) void k_hist(const int* __restrict__ et, int E, int seg,
                                              int* __restrict__ hist) {
    __shared__ int hb[T_];
    const int b = blockIdx.x, tid = threadIdx.x;
    if (tid < T_) hb[tid] = 0;
    __syncthreads();
    const int segLo = b * seg;
    const int segHi = min(E, segLo + seg);
    const int per = (seg + STH - 1) / STH;
    const int lo = segLo + tid * per;
    const int hi = min(segHi, lo + per);
    int c[T_];
#pragma unroll
    for (int j = 0; j < T_; ++j) c[j] = 0;
    for (int i = lo; i < hi; ++i) {
        int ty = et[i];
#pragma unroll
        for (int j = 0; j < T_; ++j) c[j] += (ty == j) ? 1 : 0;
    }
#pragma unroll
    for (int j = 0; j < T_; ++j)
        if (c[j]) atomicAdd(&hb[j], c[j]);
    __syncthreads();
    if (tid < T_) hist[b * T_ + tid] = hb[tid];
}

// ---------------------------------------------------------------------------
// K2: scan over SB segment histograms (one block of SB threads).
// Produces typeBase/typeCount/tileBase and rewrites hist -> blockBase[b][t].
// ---------------------------------------------------------------------------
__global__ __launch_bounds__(SB) void k_scan(int* __restrict__ hist,
                                             int* __restrict__ typeBase,
                                             int* __restrict__ typeCount,
                                             int* __restrict__ tileBase) {
    __shared__ int sc[SB][T_ + 1];   // stride 9 -> conflict-free
    __shared__ int sbase[T_];
    const int tid = threadIdx.x;
#pragma unroll
    for (int j = 0; j < T_; ++j) sc[tid][j] = hist[tid * T_ + j];
    __syncthreads();
    for (int ofs = 1; ofs < SB; ofs <<= 1) {
        int v[T_];
        if (tid >= ofs) {
#pragma unroll
            for (int j = 0; j < T_; ++j) v[j] = sc[tid - ofs][j];
        }
        __syncthreads();
        if (tid >= ofs) {
#pragma unroll
            for (int j = 0; j < T_; ++j) sc[tid][j] += v[j];
        }
        __syncthreads();
    }
    if (tid == 0) {
        int b = 0, tb = 0;
#pragma unroll
        for (int j = 0; j < T_; ++j) {
            int cntj = sc[SB - 1][j];
            sbase[j] = b;
            typeBase[j] = b;
            typeCount[j] = cntj;
            tileBase[j] = tb;
            b += cntj;
            tb += (cntj + TE - 1) / TE;
        }
        tileBase[T_] = tb;
    }
    __syncthreads();
#pragma unroll
    for (int j = 0; j < T_; ++j)
        hist[tid * T_ + j] = sbase[j] + (tid ? sc[tid - 1][j] : 0);
}

// ---------------------------------------------------------------------------
// K3: stable scatter. SB blocks x STH threads, same segmentation as K1.
// ---------------------------------------------------------------------------
__global__ __launch_bounds__(STH) void k_scatter(const int* __restrict__ et, int E, int seg,
                                                 const int* __restrict__ blockBase,
                                                 int* __restrict__ sorted_e) {
    __shared__ int sc[STH][T_ + 1];
    const int b = blockIdx.x, tid = threadIdx.x;
    const int segLo = b * seg;
    const int segHi = min(E, segLo + seg);
    const int per = (seg + STH - 1) / STH;
    const int lo = segLo + tid * per;
    const int hi = min(segHi, lo + per);
    int c[T_];
#pragma unroll
    for (int j = 0; j < T_; ++j) c[j] = 0;
    for (int i = lo; i < hi; ++i) {
        int ty = et[i];
#pragma unroll
        for (int j = 0; j < T_; ++j) c[j] += (ty == j) ? 1 : 0;
    }
#pragma unroll
    for (int j = 0; j < T_; ++j) sc[tid][j] = c[j];
    __syncthreads();
    for (int ofs = 1; ofs < STH; ofs <<= 1) {
        int v[T_];
        if (tid >= ofs) {
#pragma unroll
            for (int j = 0; j < T_; ++j) v[j] = sc[tid - ofs][j];
        }
        __syncthreads();
        if (tid >= ofs) {
#pragma unroll
            for (int j = 0; j < T_; ++j) sc[tid][j] += v[j];
        }
        __syncthreads();
    }
    int p[T_];
#pragma unroll
    for (int j = 0; j < T_; ++j)
        p[j] = blockBase[b * T_ + j] + (tid ? sc[tid - 1][j] : 0);
    for (int i = lo; i < hi; ++i) {
        int ty = et[i];
        int r = 0;
#pragma unroll
        for (int j = 0; j < T_; ++j) {
            if (ty == j) { r = p[j]; p[j] = r + 1; }
        }
        sorted_e[r] = i;
    }
}

// ---------------------------------------------------------------------------
// Main fused kernel, v5 = v4 with DE-PERMUTED h_save stores.
// R4 counters showed the whole traffic anomaly = h_save 16B stores
// transacting sub-line (8x write amp + RFO fetch). Cause: the source-side
// XOR swizzle leaked lane-permuted addresses into the store path. Fix:
// read back the LDS slot holding the LINEAR column (conflict-free quad
// permutation) and store lane-ASCENDING so each 8-lane group is one
// consecutive 128B run. Loads keep the swizzled source (fetch side was
// never amplified).
// ---------------------------------------------------------------------------
__global__ __launch_bounds__(NTH, 4) void k_main(
    const float* __restrict__ h,
    const float* __restrict__ srcW, const float* __restrict__ srcB,
    const float* __restrict__ dstW, const float* __restrict__ dstB,
    const float* __restrict__ outW, const float* __restrict__ outB,
    const int* __restrict__ sorted_e,
    const int* __restrict__ typeBase, const int* __restrict__ typeCount,
    const int* __restrict__ tileBase,
    float* __restrict__ out, int E)
{
    const int b = blockIdx.x;
    if (b >= tileBase[T_]) return;
    int t = 0;
#pragma unroll
    for (int j = 1; j < T_; ++j) t += (b >= tileBase[j]) ? 1 : 0;
    const int i0   = (b - tileBase[t]) * TE;
    const int cnt  = typeCount[t];
    const int base = typeBase[t];
    const int tid = threadIdx.x;
    const int tx  = tid & 15;
    const int ty  = tid >> 4;          // 0..63

    // stage: [buf][m*1024 + r*8 + s8] float4; LDS slot s8 of row r holds
    // global f4-column s8 ^ (r&7) (XOR within the 128B row line).
    __shared__ __align__(16) float4 stg[2][3 * TE * (DC / 4)];   // 98304 B
    __shared__ int eIdx[TE];

    if (tid < TE) {
        int p = i0 + tid;
        eIdx[tid] = sorted_e[base + (p < cnt ? p : i0)];  // clamp pads to valid edge
    }
    __syncthreads();

    const int r   = tid >> 3;                 // staged row (edge slot) 0..127
    const int s8  = tid & 7;                  // f4 slot within row
    const int c4  = s8 ^ (r & 7);             // swizzled global f4-column (loads)
    const bool g  = (i0 + r) < cnt;
    const float* gsrc[3];
#pragma unroll
    for (int m = 0; m < 3; ++m)
        gsrc[m] = h + ((size_t)m * E + eIdx[r]) * D_ + (c4 << 2);

    // h_save: LINEAR (ascending) column s8 per lane; slot holding col s8 is
    // r*8 + (s8 ^ (r&7)) = r*8 + c4.
    float* const outH = out + (size_t)4 * E;        // h_save region
    float* gHS[2];
#pragma unroll
    for (int m = 0; m < 2; ++m)
        gHS[m] = outH + ((size_t)m * E + eIdx[r]) * D_ + (s8 << 2);
    const int slotLin = r * 8 + c4;

    float4* const st0 = &stg[0][0];
    float4* const st1 = &stg[1][0];

    auto stage_issue = [&](float4* dstF4, int d0c) {
#pragma unroll
        for (int m = 0; m < 3; ++m) {
            __builtin_amdgcn_global_load_lds(
                (const __attribute__((address_space(1))) void*)(gsrc[m] + d0c),
                (__attribute__((address_space(3))) void*)(dstF4 + m * NTH + tid),
                16, 0, 0);
        }
    };

    float accS[2][7], accP[2][7], accN[2][7];
#pragma unroll
    for (int kk = 0; kk < 2; ++kk)
#pragma unroll
        for (int jj = 0; jj < 7; ++jj) { accS[kk][jj] = 0.f; accP[kk][jj] = 0.f; accN[kk][jj] = 0.f; }

    int jcs[7];
#pragma unroll
    for (int jj = 0; jj < 7; ++jj) {
        int j = jj * 16 + tx;
        jcs[jj] = (j < H_) ? j : (H_ - 1);   // clamp; clamped result zeroed later
    }

    int rowB[2], swk[2];
#pragma unroll
    for (int kk = 0; kk < 2; ++kk) {
        int rr = ty * 2 + kk;                // this thread's compute rows 0..127
        rowB[kk] = rr * 8;
        swk[kk]  = rr & 7;
    }

    const float* wsBase = srcW + (size_t)t * D_ * H_;
    const float* wdBase = dstW + (size_t)t * D_ * H_;

    stage_issue(st0, 0);   // prologue: chunk 0

#pragma unroll 1
    for (int ch = 0; ch < NC; ++ch) {
        const int d0 = ch * DC;
        float4* const cs = (ch & 1) ? st1 : st0;
        float4* const ns = (ch & 1) ? st0 : st1;

        __syncthreads();   // chunk-ch staging complete (issued one chunk ago)

        if (ch + 1 < NC) stage_issue(ns, d0 + DC);

        // fused h_save: de-permuted readback (uniform bank-quad permutation,
        // conflict-free) + lane-ASCENDING store = full 128B runs per 8-lane
        // group -> line-granular write transactions.
#pragma unroll
        for (int m = 0; m < 2; ++m) {
            float4 v = cs[m * NTH + slotLin];
            if (g) *(float4*)(gHS[m] + d0) = v;
        }

        const float* pws = wsBase + (size_t)d0 * H_;
        const float* pwd = wdBase + (size_t)d0 * H_;
#pragma unroll
        for (int dd4 = 0; dd4 < DC / 4; ++dd4) {
            float4 Av[3][2];
#pragma unroll
            for (int m = 0; m < 3; ++m)
#pragma unroll
                for (int kk = 0; kk < 2; ++kk)
                    Av[m][kk] = cs[m * NTH + rowB[kk] + (dd4 ^ swk[kk])];
#pragma unroll
            for (int q = 0; q < 4; ++q) {
                const int d = dd4 * 4 + q;
                float wsv[7], wdv[7];
#pragma unroll
                for (int jj = 0; jj < 7; ++jj) {
                    wsv[jj] = pws[d * H_ + jcs[jj]];
                    wdv[jj] = pwd[d * H_ + jcs[jj]];
                }
#pragma unroll
                for (int kk = 0; kk < 2; ++kk) {
                    float as = ((const float*)&Av[0][kk])[q];
                    float ap = ((const float*)&Av[1][kk])[q];
                    float an = ((const float*)&Av[2][kk])[q];
#pragma unroll
                    for (int jj = 0; jj < 7; ++jj) {
                        accS[kk][jj] = fmaf(as, wsv[jj], accS[kk][jj]);
                        accP[kk][jj] = fmaf(ap, wdv[jj], accP[kk][jj]);
                        accN[kk][jj] = fmaf(an, wdv[jj], accN[kk][jj]);
                    }
                }
            }
        }
    }

    // ---- epilogue: bias + relu + out-layer, all in registers ----
    float sb[7], db[7], woA[7], woB[7];
#pragma unroll
    for (int jj = 0; jj < 7; ++jj) {
        sb[jj] = srcB[t * H_ + jcs[jj]];
        db[jj] = dstB[t * H_ + jcs[jj]];
        float2 wo = *(const float2*)(outW + (size_t)t * H_ * C_ + jcs[jj] * C_);
        woA[jj] = wo.x; woB[jj] = wo.y;
    }

    float part[8];   // part[kk*4 + pn*2 + c]
#pragma unroll
    for (int i = 0; i < 8; ++i) part[i] = 0.f;
#pragma unroll
    for (int kk = 0; kk < 2; ++kk) {
#pragma unroll
        for (int jj = 0; jj < 7; ++jj) {
            float s_ = accS[kk][jj] + sb[jj];
            float pe = fmaxf(s_ + accP[kk][jj] + db[jj], 0.f);
            float ne = fmaxf(s_ + accN[kk][jj] + db[jj], 0.f);
            if (jj == 6) {                    // zero clamped duplicate columns
                bool valid = (tx < 4);
                pe = valid ? pe : 0.f;
                ne = valid ? ne : 0.f;
            }
            part[kk * 4 + 0] = fmaf(pe, woA[jj], part[kk * 4 + 0]);
            part[kk * 4 + 1] = fmaf(pe, woB[jj], part[kk * 4 + 1]);
            part[kk * 4 + 2] = fmaf(ne, woA[jj], part[kk * 4 + 2]);
            part[kk * 4 + 3] = fmaf(ne, woB[jj], part[kk * 4 + 3]);
        }
    }

    // 16-lane butterfly: selector bits (c, pn, kk) from tx; lanes tx and tx+8
    // end duplicated -> guard tx<8.
    float v4[4];
#pragma unroll
    for (int a = 0; a < 4; ++a) {
        float keep = (tx & 1) ? part[2 * a + 1] : part[2 * a];
        float send = (tx & 1) ? part[2 * a] : part[2 * a + 1];
        v4[a] = keep + __shfl_xor(send, 1);
    }
    float v2_[2];
#pragma unroll
    for (int a = 0; a < 2; ++a) {
        float keep = (tx & 2) ? v4[2 * a + 1] : v4[2 * a];
        float send = (tx & 2) ? v4[2 * a] : v4[2 * a + 1];
        v2_[a] = keep + __shfl_xor(send, 2);
    }
    {
        float keep = (tx & 4) ? v2_[1] : v2_[0];
        float send = (tx & 4) ? v2_[0] : v2_[1];
        float v1 = keep + __shfl_xor(send, 4);
        float tot = v1 + __shfl_xor(v1, 8);

        const int c   = tx & 1;
        const int pn  = (tx >> 1) & 1;
        const int kkO = (tx >> 2) & 1;
        const int k   = ty * 2 + kkO;
        if (tx < 8 && (i0 + k) < cnt) {
            float val = tot + outB[t * C_ + c];
            size_t pidx = (size_t)(base + i0 + k) * C_ + c;
            out[(pn ? (size_t)C_ * E : (size_t)0) + pidx] = val;
        }
    }
}

// ---------------------------------------------------------------------------
extern "C" void kernel_launch(void* const* d_in, const int* in_sizes, int n_in,
                              void* d_out, int out_size, void* d_ws, size_t ws_size,
                              hipStream_t stream) {
    (void)n_in; (void)out_size; (void)ws_size;
    const float* h    = (const float*)d_in[0];
    const float* srcW = (const float*)d_in[1];
    const float* srcB = (const float*)d_in[2];
    const float* dstW = (const float*)d_in[3];
    const float* dstB = (const float*)d_in[4];
    const float* outW = (const float*)d_in[5];
    const float* outB = (const float*)d_in[6];
    const int*   et   = (const int*)d_in[7];
    const int E = in_sizes[7];

    float* out = (float*)d_out;
    int* ws = (int*)d_ws;
    int* typeBase  = ws;
    int* typeCount = ws + 8;
    int* tileBase  = ws + 16;
    int* hist      = ws + WS_HIST;
    int* sorted_e  = ws + WS_SORTED;

    const int seg = (E + SB - 1) / SB;
    k_hist<<<SB, STH, 0, stream>>>(et, E, seg, hist);
    k_scan<<<1, SB, 0, stream>>>(hist, typeBase, typeCount, tileBase);
    k_scatter<<<SB, STH, 0, stream>>>(et, E, seg, hist, sorted_e);

    const int maxTiles = (E + TE - 1) / TE + T_;   // >= sum of per-type ceil tiles
    k_main<<<maxTiles, NTH, 0, stream>>>(h, srcW, srcB, dstW, dstB, outW, outB,
                                         sorted_e, typeBase, typeCount, tileBase,
                                         out, E);
}

// Round 6
// 1801.667 us; speedup vs baseline: 1.9707x; 1.9645x over previous
//
#include <hip/hip_runtime.h>

// Problem constants (from reference): T=8, D=512, H=100, C=2, NEG=1
constexpr int D_ = 512;
constexpr int H_ = 100;
constexpr int C_ = 2;
constexpr int T_ = 8;

constexpr int TE  = 128;        // edges per block
constexpr int DC  = 32;         // D-chunk (floats) = one 128B line per row
constexpr int NC  = D_ / DC;    // 16 chunks
constexpr int NTH = 256;        // threads per main block (4 waves -> SAFE traffic regime)
constexpr int SB  = 128;        // sort segments / blocks
constexpr int STH = 256;        // threads per sort block

// ws layout (ints): [0:8) typeBase | [8:16) typeCount | [16:25) tileBase
//                   [32:32+SB*8) hist/blockBase | [1056 : 1056+E) sorted_e
constexpr int WS_HIST = 32;
constexpr int WS_SORTED = 32 + SB * T_;   // 1056

// ---------------------------------------------------------------------------
// K1: per-segment histogram. SB blocks x STH threads.
// ---------------------------------------------------------------------------
__global__ __launch_bounds__(STH) void k_hist(const int* __restrict__ et, int E, int seg,
                                              int* __restrict__ hist) {
    __shared__ int hb[T_];
    const int b = blockIdx.x, tid = threadIdx.x;
    if (tid < T_) hb[tid] = 0;
    __syncthreads();
    const int segLo = b * seg;
    const int segHi = min(E, segLo + seg);
    const int per = (seg + STH - 1) / STH;
    const int lo = segLo + tid * per;
    const int hi = min(segHi, lo + per);
    int c[T_];
#pragma unroll
    for (int j = 0; j < T_; ++j) c[j] = 0;
    for (int i = lo; i < hi; ++i) {
        int ty = et[i];
#pragma unroll
        for (int j = 0; j < T_; ++j) c[j] += (ty == j) ? 1 : 0;
    }
#pragma unroll
    for (int j = 0; j < T_; ++j)
        if (c[j]) atomicAdd(&hb[j], c[j]);
    __syncthreads();
    if (tid < T_) hist[b * T_ + tid] = hb[tid];
}

// ---------------------------------------------------------------------------
// K2: scan over SB segment histograms (one block of SB threads).
// ---------------------------------------------------------------------------
__global__ __launch_bounds__(SB) void k_scan(int* __restrict__ hist,
                                             int* __restrict__ typeBase,
                                             int* __restrict__ typeCount,
                                             int* __restrict__ tileBase) {
    __shared__ int sc[SB][T_ + 1];   // stride 9 -> conflict-free
    __shared__ int sbase[T_];
    const int tid = threadIdx.x;
#pragma unroll
    for (int j = 0; j < T_; ++j) sc[tid][j] = hist[tid * T_ + j];
    __syncthreads();
    for (int ofs = 1; ofs < SB; ofs <<= 1) {
        int v[T_];
        if (tid >= ofs) {
#pragma unroll
            for (int j = 0; j < T_; ++j) v[j] = sc[tid - ofs][j];
        }
        __syncthreads();
        if (tid >= ofs) {
#pragma unroll
            for (int j = 0; j < T_; ++j) sc[tid][j] += v[j];
        }
        __syncthreads();
    }
    if (tid == 0) {
        int b = 0, tb = 0;
#pragma unroll
        for (int j = 0; j < T_; ++j) {
            int cntj = sc[SB - 1][j];
            sbase[j] = b;
            typeBase[j] = b;
            typeCount[j] = cntj;
            tileBase[j] = tb;
            b += cntj;
            tb += (cntj + TE - 1) / TE;
        }
        tileBase[T_] = tb;
    }
    __syncthreads();
#pragma unroll
    for (int j = 0; j < T_; ++j)
        hist[tid * T_ + j] = sbase[j] + (tid ? sc[tid - 1][j] : 0);
}

// ---------------------------------------------------------------------------
// K3: stable scatter. SB blocks x STH threads, same segmentation as K1.
// ---------------------------------------------------------------------------
__global__ __launch_bounds__(STH) void k_scatter(const int* __restrict__ et, int E, int seg,
                                                 const int* __restrict__ blockBase,
                                                 int* __restrict__ sorted_e) {
    __shared__ int sc[STH][T_ + 1];
    const int b = blockIdx.x, tid = threadIdx.x;
    const int segLo = b * seg;
    const int segHi = min(E, segLo + seg);
    const int per = (seg + STH - 1) / STH;
    const int lo = segLo + tid * per;
    const int hi = min(segHi, lo + per);
    int c[T_];
#pragma unroll
    for (int j = 0; j < T_; ++j) c[j] = 0;
    for (int i = lo; i < hi; ++i) {
        int ty = et[i];
#pragma unroll
        for (int j = 0; j < T_; ++j) c[j] += (ty == j) ? 1 : 0;
    }
#pragma unroll
    for (int j = 0; j < T_; ++j) sc[tid][j] = c[j];
    __syncthreads();
    for (int ofs = 1; ofs < STH; ofs <<= 1) {
        int v[T_];
        if (tid >= ofs) {
#pragma unroll
            for (int j = 0; j < T_; ++j) v[j] = sc[tid - ofs][j];
        }
        __syncthreads();
        if (tid >= ofs) {
#pragma unroll
            for (int j = 0; j < T_; ++j) sc[tid][j] += v[j];
        }
        __syncthreads();
    }
    int p[T_];
#pragma unroll
    for (int j = 0; j < T_; ++j)
        p[j] = blockBase[b * T_ + j] + (tid ? sc[tid - 1][j] : 0);
    for (int i = lo; i < hi; ++i) {
        int ty = et[i];
        int r = 0;
#pragma unroll
        for (int j = 0; j < T_; ++j) {
            if (ty == j) { r = p[j]; p[j] = r + 1; }
        }
        sorted_e[r] = i;
    }
}

// ---------------------------------------------------------------------------
// Main fused kernel, v6. Stay in the traffic-safe regime (256 threads,
// 1 block/CU via 147 KB LDS -> ~4 waves/CU, the only point measured at
// logical HBM traffic) and remove R1's limiter: weight loads now staged in
// LDS (double-buffered, chunk-ahead prefetch hides latency) and TE=128
// (8 edges/thread) doubles FMA per weight-read. All global access stays
// full-128B-line: h loads swizzled-source, h_save ascending, weights
// contiguous streams.
// ---------------------------------------------------------------------------
__global__ __launch_bounds__(NTH, 1) void k_main(
    const float* __restrict__ h,
    const float* __restrict__ srcW, const float* __restrict__ srcB,
    const float* __restrict__ dstW, const float* __restrict__ dstB,
    const float* __restrict__ outW, const float* __restrict__ outB,
    const int* __restrict__ sorted_e,
    const int* __restrict__ typeBase, const int* __restrict__ typeCount,
    const int* __restrict__ tileBase,
    float* __restrict__ out, int E)
{
    const int b = blockIdx.x;
    if (b >= tileBase[T_]) return;
    int t = 0;
#pragma unroll
    for (int j = 1; j < T_; ++j) t += (b >= tileBase[j]) ? 1 : 0;
    const int i0   = (b - tileBase[t]) * TE;
    const int cnt  = typeCount[t];
    const int base = typeBase[t];
    const int tid = threadIdx.x;
    const int tx  = tid & 15;
    const int ty  = tid >> 4;          // 0..15

    // stgH: [buf][m*1024 + r*8 + s8] float4; slot s8 of row r holds global
    // f4-col s8 ^ sw(r), sw(r) = (r ^ (r>>3)) & 7.  98304 B
    // stgW: [buf][mat*800 + i] float4, linear (srcW then dstW chunk). 51200 B
    __shared__ __align__(16) float4 stgH[2][3 * TE * (DC / 4)];
    __shared__ __align__(16) float4 stgW[2][2 * (DC * H_ / 4)];
    __shared__ int eIdx[TE];

    if (tid < TE) {
        int p = i0 + tid;
        eIdx[tid] = sorted_e[base + (p < cnt ? p : i0)];  // clamp pads to valid edge
    }
    __syncthreads();

    const int r0 = tid >> 3;              // base staged row 0..31
    const int s8 = tid & 7;               // f4 slot within row
    const size_t mStride = (size_t)E * D_;
    float* const outH = out + (size_t)4 * E;    // h_save region

    const float* rowSrc[4];               // swizzled-col h source per row
    float*       rowHS[4];                // ascending-col h_save dest per row
    int slotLin[4];                       // LDS slot holding LINEAR col s8
    bool gok[4];
#pragma unroll
    for (int rr4 = 0; rr4 < 4; ++rr4) {
        int rr = r0 + rr4 * 32;
        int sw = (rr ^ (rr >> 3)) & 7;
        int c4 = s8 ^ sw;
        int e  = eIdx[rr];
        rowSrc[rr4]  = h    + (size_t)e * D_ + (c4 << 2);
        rowHS[rr4]   = outH + (size_t)e * D_ + (s8 << 2);
        slotLin[rr4] = rr * 8 + c4;
        gok[rr4]     = (i0 + rr) < cnt;
    }

    const float* wsBase = srcW + (size_t)t * D_ * H_;
    const float* wdBase = dstW + (size_t)t * D_ * H_;

    auto stage_issue = [&](int buf, int d0c) {
        float4* dH = &stgH[buf][0];
#pragma unroll
        for (int m = 0; m < 3; ++m)
#pragma unroll
            for (int rr4 = 0; rr4 < 4; ++rr4)
                __builtin_amdgcn_global_load_lds(
                    (const __attribute__((address_space(1))) void*)(rowSrc[rr4] + m * mStride + d0c),
                    (__attribute__((address_space(3))) void*)(dH + m * 1024 + rr4 * 256 + tid),
                    16, 0, 0);
        // weights: 800 f4 per matrix per chunk; rounds {0,256,512,544}, last
        // overlaps (544..767 double-written same data) to avoid exec-masking.
        const float4* wS = (const float4*)(wsBase + (size_t)d0c * H_);
        const float4* wD = (const float4*)(wdBase + (size_t)d0c * H_);
        float4* dW = &stgW[buf][0];
#pragma unroll
        for (int rr = 0; rr < 4; ++rr) {
            const int wo = (rr == 0) ? 0 : (rr == 1) ? 256 : (rr == 2) ? 512 : 544;
            __builtin_amdgcn_global_load_lds(
                (const __attribute__((address_space(1))) void*)(wS + wo + tid),
                (__attribute__((address_space(3))) void*)(dW + wo + tid), 16, 0, 0);
        }
#pragma unroll
        for (int rr = 0; rr < 4; ++rr) {
            const int wo = (rr == 0) ? 0 : (rr == 1) ? 256 : (rr == 2) ? 512 : 544;
            __builtin_amdgcn_global_load_lds(
                (const __attribute__((address_space(1))) void*)(wD + wo + tid),
                (__attribute__((address_space(3))) void*)(dW + 800 + wo + tid), 16, 0, 0);
        }
    };

    float accS[8][7], accP[8][7], accN[8][7];
#pragma unroll
    for (int kk = 0; kk < 8; ++kk)
#pragma unroll
        for (int jj = 0; jj < 7; ++jj) { accS[kk][jj] = 0.f; accP[kk][jj] = 0.f; accN[kk][jj] = 0.f; }

    int jcs[7];
#pragma unroll
    for (int jj = 0; jj < 7; ++jj) {
        int j = jj * 16 + tx;
        jcs[jj] = (j < H_) ? j : (H_ - 1);   // clamp; clamped result zeroed later
    }

    stage_issue(0, 0);   // prologue: chunk 0

#pragma unroll 1
    for (int ch = 0; ch < NC; ++ch) {
        const int d0 = ch * DC;
        const int cb = ch & 1;

        __syncthreads();   // chunk-ch staging complete (issued one chunk ago)

        if (ch + 1 < NC) stage_issue(cb ^ 1, d0 + DC);

        const float4* csH = &stgH[cb][0];

        // fused h_save: de-permuted readback, lane-ascending full-line stores
#pragma unroll
        for (int m = 0; m < 2; ++m)
#pragma unroll
            for (int rr4 = 0; rr4 < 4; ++rr4) {
                float4 v = csH[m * 1024 + slotLin[rr4]];
                if (gok[rr4]) *(float4*)(rowHS[rr4] + m * mStride + d0) = v;
            }

        const float* lwS = (const float*)&stgW[cb][0];   // [32][100] src weights
        const float* lwD = lwS + DC * H_;                // [32][100] dst weights
#pragma unroll
        for (int dd4 = 0; dd4 < DC / 4; ++dd4) {
            float4 Av[3][8];
#pragma unroll
            for (int m = 0; m < 3; ++m)
#pragma unroll
                for (int kk = 0; kk < 8; ++kk)
                    Av[m][kk] = csH[m * 1024 + (ty * 8 + kk) * 8 + (dd4 ^ ((kk ^ ty) & 7))];
#pragma unroll
            for (int q = 0; q < 4; ++q) {
                const int d = dd4 * 4 + q;
                float wsv[7], wdv[7];
#pragma unroll
                for (int jj = 0; jj < 7; ++jj) {
                    wsv[jj] = lwS[d * H_ + jcs[jj]];
                    wdv[jj] = lwD[d * H_ + jcs[jj]];
                }
#pragma unroll
                for (int kk = 0; kk < 8; ++kk) {
                    float as = ((const float*)&Av[0][kk])[q];
                    float ap = ((const float*)&Av[1][kk])[q];
                    float an = ((const float*)&Av[2][kk])[q];
#pragma unroll
                    for (int jj = 0; jj < 7; ++jj) {
                        accS[kk][jj] = fmaf(as, wsv[jj], accS[kk][jj]);
                        accP[kk][jj] = fmaf(ap, wdv[jj], accP[kk][jj]);
                        accN[kk][jj] = fmaf(an, wdv[jj], accN[kk][jj]);
                    }
                }
            }
        }
    }

    // ---- epilogue: bias + relu + out-layer, all in registers ----
    float sb[7], db[7], woA[7], woB[7];
#pragma unroll
    for (int jj = 0; jj < 7; ++jj) {
        sb[jj] = srcB[t * H_ + jcs[jj]];
        db[jj] = dstB[t * H_ + jcs[jj]];
        float2 wo = *(const float2*)(outW + (size_t)t * H_ * C_ + jcs[jj] * C_);
        woA[jj] = wo.x; woB[jj] = wo.y;
    }

#pragma unroll
    for (int half = 0; half < 2; ++half) {
        float part[16];   // part[kkL*4 + pn*2 + c]
#pragma unroll
        for (int i = 0; i < 16; ++i) part[i] = 0.f;
#pragma unroll
        for (int kkL = 0; kkL < 4; ++kkL) {
            const int kk = half * 4 + kkL;
#pragma unroll
            for (int jj = 0; jj < 7; ++jj) {
                float s_ = accS[kk][jj] + sb[jj];
                float pe = fmaxf(s_ + accP[kk][jj] + db[jj], 0.f);
                float ne = fmaxf(s_ + accN[kk][jj] + db[jj], 0.f);
                if (jj == 6) {                    // zero clamped duplicate columns
                    bool valid = (tx < 4);
                    pe = valid ? pe : 0.f;
                    ne = valid ? ne : 0.f;
                }
                part[kkL * 4 + 0] = fmaf(pe, woA[jj], part[kkL * 4 + 0]);
                part[kkL * 4 + 1] = fmaf(pe, woB[jj], part[kkL * 4 + 1]);
                part[kkL * 4 + 2] = fmaf(ne, woA[jj], part[kkL * 4 + 2]);
                part[kkL * 4 + 3] = fmaf(ne, woB[jj], part[kkL * 4 + 3]);
            }
        }
        // 16-lane butterfly (verified in R2): lane tx ends with output
        // (c=tx&1, pn=(tx>>1)&1, kkO=tx>>2)
        float v8[8];
#pragma unroll
        for (int a = 0; a < 8; ++a) {
            float keep = (tx & 1) ? part[2 * a + 1] : part[2 * a];
            float send = (tx & 1) ? part[2 * a] : part[2 * a + 1];
            v8[a] = keep + __shfl_xor(send, 1);
        }
        float v4[4];
#pragma unroll
        for (int a = 0; a < 4; ++a) {
            float keep = (tx & 2) ? v8[2 * a + 1] : v8[2 * a];
            float send = (tx & 2) ? v8[2 * a] : v8[2 * a + 1];
            v4[a] = keep + __shfl_xor(send, 2);
        }
        float v2_[2];
#pragma unroll
        for (int a = 0; a < 2; ++a) {
            float keep = (tx & 4) ? v4[2 * a + 1] : v4[2 * a];
            float send = (tx & 4) ? v4[2 * a] : v4[2 * a + 1];
            v2_[a] = keep + __shfl_xor(send, 4);
        }
        {
            float keep = (tx & 8) ? v2_[1] : v2_[0];
            float send = (tx & 8) ? v2_[0] : v2_[1];
            float tot = keep + __shfl_xor(send, 8);

            const int c   = tx & 1;
            const int pn  = (tx >> 1) & 1;
            const int kkO = tx >> 2;
            const int k   = ty * 8 + half * 4 + kkO;
            if (i0 + k < cnt) {
                float val = tot + outB[t * C_ + c];
                size_t pidx = (size_t)(base + i0 + k) * C_ + c;
                out[(pn ? (size_t)C_ * E : (size_t)0) + pidx] = val;
            }
        }
    }
}

// ---------------------------------------------------------------------------
extern "C" void kernel_launch(void* const* d_in, const int* in_sizes, int n_in,
                              void* d_out, int out_size, void* d_ws, size_t ws_size,
                              hipStream_t stream) {
    (void)n_in; (void)out_size; (void)ws_size;
    const float* h    = (const float*)d_in[0];
    const float* srcW = (const float*)d_in[1];
    const float* srcB = (const float*)d_in[2];
    const float* dstW = (const float*)d_in[3];
    const float* dstB = (const float*)d_in[4];
    const float* outW = (const float*)d_in[5];
    const float* outB = (const float*)d_in[6];
    const int*   et   = (const int*)d_in[7];
    const int E = in_sizes[7];

    float* out = (float*)d_out;
    int* ws = (int*)d_ws;
    int* typeBase  = ws;
    int* typeCount = ws + 8;
    int* tileBase  = ws + 16;
    int* hist      = ws + WS_HIST;
    int* sorted_e  = ws + WS_SORTED;

    const int seg = (E + SB - 1) / SB;
    k_hist<<<SB, STH, 0, stream>>>(et, E, seg, hist);
    k_scan<<<1, SB, 0, stream>>>(hist, typeBase, typeCount, tileBase);
    k_scatter<<<SB, STH, 0, stream>>>(et, E, seg, hist, sorted_e);

    const int maxTiles = (E + TE - 1) / TE + T_;   // >= sum of per-type ceil tiles
    k_main<<<maxTiles, NTH, 0, stream>>>(h, srcW, srcB, dstW, dstB, outW, outB,
                                         sorted_e, typeBase, typeCount, tileBase,
                                         out, E);
}

// Round 7
// 1051.426 us; speedup vs baseline: 3.3769x; 1.7135x over previous
//
#include <hip/hip_runtime.h>

// Problem constants (from reference): T=8, D=512, H=100, C=2, NEG=1
constexpr int D_ = 512;
constexpr int H_ = 100;
constexpr int C_ = 2;
constexpr int T_ = 8;

constexpr int TE  = 128;        // edges per block
constexpr int DC  = 32;         // D-chunk (floats) = one 128B line per row = one MFMA K
constexpr int NC  = D_ / DC;    // 16 chunks
constexpr int NTH = 256;        // 4 waves -> traffic-safe regime (R1/R6-proven)
constexpr int SB  = 128;        // sort segments / blocks
constexpr int STH = 256;        // threads per sort block

constexpr int WS_HIST = 32;
constexpr int WS_SORTED = 32 + SB * T_;   // 1056

typedef __attribute__((ext_vector_type(8))) short bf16x8;
typedef __attribute__((ext_vector_type(4))) float f32x4;

__device__ __forceinline__ unsigned short bfhi(float x) {
    return (unsigned short)(__builtin_bit_cast(unsigned int, x) >> 16);
}
__device__ __forceinline__ float bfback(unsigned short u) {
    return __builtin_bit_cast(float, (unsigned int)u << 16);
}

// ---------------------------------------------------------------------------
// K1: per-segment histogram. SB blocks x STH threads.
// ---------------------------------------------------------------------------
__global__ __launch_bounds__(STH) void k_hist(const int* __restrict__ et, int E, int seg,
                                              int* __restrict__ hist) {
    __shared__ int hb[T_];
    const int b = blockIdx.x, tid = threadIdx.x;
    if (tid < T_) hb[tid] = 0;
    __syncthreads();
    const int segLo = b * seg;
    const int segHi = min(E, segLo + seg);
    const int per = (seg + STH - 1) / STH;
    const int lo = segLo + tid * per;
    const int hi = min(segHi, lo + per);
    int c[T_];
#pragma unroll
    for (int j = 0; j < T_; ++j) c[j] = 0;
    for (int i = lo; i < hi; ++i) {
        int ty = et[i];
#pragma unroll
        for (int j = 0; j < T_; ++j) c[j] += (ty == j) ? 1 : 0;
    }
#pragma unroll
    for (int j = 0; j < T_; ++j)
        if (c[j]) atomicAdd(&hb[j], c[j]);
    __syncthreads();
    if (tid < T_) hist[b * T_ + tid] = hb[tid];
}

// ---------------------------------------------------------------------------
// K2: scan over SB segment histograms (one block of SB threads).
// ---------------------------------------------------------------------------
__global__ __launch_bounds__(SB) void k_scan(int* __restrict__ hist,
                                             int* __restrict__ typeBase,
                                             int* __restrict__ typeCount,
                                             int* __restrict__ tileBase) {
    __shared__ int sc[SB][T_ + 1];
    __shared__ int sbase[T_];
    const int tid = threadIdx.x;
#pragma unroll
    for (int j = 0; j < T_; ++j) sc[tid][j] = hist[tid * T_ + j];
    __syncthreads();
    for (int ofs = 1; ofs < SB; ofs <<= 1) {
        int v[T_];
        if (tid >= ofs) {
#pragma unroll
            for (int j = 0; j < T_; ++j) v[j] = sc[tid - ofs][j];
        }
        __syncthreads();
        if (tid >= ofs) {
#pragma unroll
            for (int j = 0; j < T_; ++j) sc[tid][j] += v[j];
        }
        __syncthreads();
    }
    if (tid == 0) {
        int b = 0, tb = 0;
#pragma unroll
        for (int j = 0; j < T_; ++j) {
            int cntj = sc[SB - 1][j];
            sbase[j] = b;
            typeBase[j] = b;
            typeCount[j] = cntj;
            tileBase[j] = tb;
            b += cntj;
            tb += (cntj + TE - 1) / TE;
        }
        tileBase[T_] = tb;
    }
    __syncthreads();
#pragma unroll
    for (int j = 0; j < T_; ++j)
        hist[tid * T_ + j] = sbase[j] + (tid ? sc[tid - 1][j] : 0);
}

// ---------------------------------------------------------------------------
// K3: stable scatter. SB blocks x STH threads, same segmentation as K1.
// ---------------------------------------------------------------------------
__global__ __launch_bounds__(STH) void k_scatter(const int* __restrict__ et, int E, int seg,
                                                 const int* __restrict__ blockBase,
                                                 int* __restrict__ sorted_e) {
    __shared__ int sc[STH][T_ + 1];
    const int b = blockIdx.x, tid = threadIdx.x;
    const int segLo = b * seg;
    const int segHi = min(E, segLo + seg);
    const int per = (seg + STH - 1) / STH;
    const int lo = segLo + tid * per;
    const int hi = min(segHi, lo + per);
    int c[T_];
#pragma unroll
    for (int j = 0; j < T_; ++j) c[j] = 0;
    for (int i = lo; i < hi; ++i) {
        int ty = et[i];
#pragma unroll
        for (int j = 0; j < T_; ++j) c[j] += (ty == j) ? 1 : 0;
    }
#pragma unroll
    for (int j = 0; j < T_; ++j) sc[tid][j] = c[j];
    __syncthreads();
    for (int ofs = 1; ofs < STH; ofs <<= 1) {
        int v[T_];
        if (tid >= ofs) {
#pragma unroll
            for (int j = 0; j < T_; ++j) v[j] = sc[tid - ofs][j];
        }
        __syncthreads();
        if (tid >= ofs) {
#pragma unroll
            for (int j = 0; j < T_; ++j) sc[tid][j] += v[j];
        }
        __syncthreads();
    }
    int p[T_];
#pragma unroll
    for (int j = 0; j < T_; ++j)
        p[j] = blockBase[b * T_ + j] + (tid ? sc[tid - 1][j] : 0);
    for (int i = lo; i < hi; ++i) {
        int ty = et[i];
        int r = 0;
#pragma unroll
        for (int j = 0; j < T_; ++j) {
            if (ty == j) { r = p[j]; p[j] = r + 1; }
        }
        sorted_e[r] = i;
    }
}

// ---------------------------------------------------------------------------
// 16-lane butterfly fold: lane ln (0..15) ends with sum of v[idx] where
// idx bits: [0]=ln&1, [1:2]=(ln>>1)&3, [3]=(ln>>3)&1.
// ---------------------------------------------------------------------------
__device__ __forceinline__ float fold16(float (&v)[16], int ln) {
    float v8[8];
#pragma unroll
    for (int a = 0; a < 8; ++a) {
        float keep = (ln & 1) ? v[2 * a + 1] : v[2 * a];
        float send = (ln & 1) ? v[2 * a] : v[2 * a + 1];
        v8[a] = keep + __shfl_xor(send, 1);
    }
    float v4[4];
#pragma unroll
    for (int a = 0; a < 4; ++a) {
        float keep = (ln & 2) ? v8[2 * a + 1] : v8[2 * a];
        float send = (ln & 2) ? v8[2 * a] : v8[2 * a + 1];
        v4[a] = keep + __shfl_xor(send, 2);
    }
    float v2[2];
#pragma unroll
    for (int a = 0; a < 2; ++a) {
        float keep = (ln & 4) ? v4[2 * a + 1] : v4[2 * a];
        float send = (ln & 4) ? v4[2 * a] : v4[2 * a + 1];
        v2[a] = keep + __shfl_xor(send, 4);
    }
    float keep = (ln & 8) ? v2[1] : v2[0];
    float send = (ln & 8) ? v2[0] : v2[1];
    return keep + __shfl_xor(send, 8);
}

// ---------------------------------------------------------------------------
// Main fused kernel, v7: MFMA split-bf16 (hi*whi + hi*wlo + lo*whi) at the
// traffic-safe 4-waves/CU point. h staging/swizzle/h_save identical to R6.
// Weights: gll fp32 -> LDS, per-chunk convert to transposed bf16 hi/lo
// W^T[n][32] (consecutive-u32 writes, conflict-free), read as B-frags via
// one ds_read_b128. M-tiles 0..23 = [src|pos|neg]x8; wave w owns tiles
// == w (mod 4) so src/pos/neg rows of an edge are lane-aligned -> in-lane
// relu-combine + in-register out-layer + 16-lane butterfly.
// MFMA 16x16x32 layouts: A row=l&15, k=(l>>4)*8+j; B col=l&15, same k-map
// (k-map errors cancel if A/B agree); C col=l&15, row=(l>>4)*4+reg
// (HW-verified mapping).
// ---------------------------------------------------------------------------
__global__ __launch_bounds__(NTH, 1) void k_main(
    const float* __restrict__ h,
    const float* __restrict__ srcW, const float* __restrict__ srcB,
    const float* __restrict__ dstW, const float* __restrict__ dstB,
    const float* __restrict__ outW, const float* __restrict__ outB,
    const int* __restrict__ sorted_e,
    const int* __restrict__ typeBase, const int* __restrict__ typeCount,
    const int* __restrict__ tileBase,
    float* __restrict__ out, int E)
{
    const int b = blockIdx.x;
    if (b >= tileBase[T_]) return;
    int t = 0;
#pragma unroll
    for (int j = 1; j < T_; ++j) t += (b >= tileBase[j]) ? 1 : 0;
    const int i0   = (b - tileBase[t]) * TE;
    const int cnt  = typeCount[t];
    const int base = typeBase[t];
    const int tid = threadIdx.x;
    const int w   = tid >> 6;          // wave 0..3
    const int l   = tid & 63;
    const int ln  = l & 15;            // tile row (A) / col (B,C)
    const int lg  = l >> 4;            // k-group 0..3

    __shared__ __align__(16) float4 stgH[2][3 * TE * (DC / 4)];      // 98304 B
    __shared__ __align__(16) float  stgWf[1792 * 4];                 // 28672 B
    __shared__ __align__(16) unsigned short wT[2 * 2 * 112 * 32];    // 28672 B
    __shared__ int eIdx[TE];

    if (tid < TE) {
        int p = i0 + tid;
        eIdx[tid] = sorted_e[base + (p < cnt ? p : i0)];  // clamp pads to valid edge
    }
    __syncthreads();

    // ---- h staging geometry (R6-proven) ----
    const int r0 = tid >> 3, s8 = tid & 7;
    const size_t mStride = (size_t)E * D_;
    float* const outH = out + (size_t)4 * E;
    const float* rowSrc[4]; float* rowHS[4]; int slotLin[4]; bool gok[4];
#pragma unroll
    for (int rr4 = 0; rr4 < 4; ++rr4) {
        int rr = r0 + rr4 * 32;
        int sw = (rr ^ (rr >> 3)) & 7;
        int c4 = s8 ^ sw;
        int e  = eIdx[rr];
        rowSrc[rr4]  = h    + (size_t)e * D_ + (c4 << 2);
        rowHS[rr4]   = outH + (size_t)e * D_ + (s8 << 2);
        slotLin[rr4] = rr * 8 + c4;
        gok[rr4]     = (i0 + rr) < cnt;
    }

    const float* wsBase = srcW + (size_t)t * D_ * H_;
    const float* wdBase = dstW + (size_t)t * D_ * H_;

    auto stageH = [&](int buf, int d0c) {
        float4* dH = &stgH[buf][0];
#pragma unroll
        for (int m = 0; m < 3; ++m)
#pragma unroll
            for (int rr4 = 0; rr4 < 4; ++rr4)
                __builtin_amdgcn_global_load_lds(
                    (const __attribute__((address_space(1))) void*)(rowSrc[rr4] + m * mStride + d0c),
                    (__attribute__((address_space(3))) void*)(dH + m * 1024 + rr4 * 256 + tid),
                    16, 0, 0);
    };
    auto stageW = [&](int d0c) {
        const float4* wS = (const float4*)(wsBase + (size_t)d0c * H_);
        const float4* wD = (const float4*)(wdBase + (size_t)d0c * H_);
        float4* dW = (float4*)stgWf;
#pragma unroll
        for (int r = 0; r < 7; ++r) {
            int flat = r * 256 + tid;
            const float4* src = (flat < 800) ? (wS + flat)
                              : ((flat < 1600) ? (wD + (flat - 800)) : (wD + 799));
            __builtin_amdgcn_global_load_lds(
                (const __attribute__((address_space(1))) void*)src,
                (__attribute__((address_space(3))) void*)(dW + flat),
                16, 0, 0);
        }
    };

    f32x4 acc[6][7];
#pragma unroll
    for (int a = 0; a < 6; ++a)
#pragma unroll
        for (int nt = 0; nt < 7; ++nt) acc[a][nt] = (f32x4){0.f, 0.f, 0.f, 0.f};

    stageH(0, 0);
    stageW(0);

    unsigned* const wTu = (unsigned*)wT;

#pragma unroll 1
    for (int ch = 0; ch < NC; ++ch) {
        const int d0 = ch * DC;
        const int cb = ch & 1;

        __syncthreads();   // (A) gll h(ch), W(ch) landed; wT free (prev MFMA done)

        const float4* csH = &stgH[cb][0];

        // fused h_save: de-permuted readback, ascending full-line stores (R6)
#pragma unroll
        for (int m = 0; m < 2; ++m)
#pragma unroll
            for (int rr4 = 0; rr4 < 4; ++rr4) {
                float4 v = csH[m * 1024 + slotLin[rr4]];
                if (gok[rr4]) *(float4*)(rowHS[rr4] + m * mStride + d0) = v;
            }

        // W convert: fp32 [d][100] -> W^T bf16 hi/lo [mat][hl][n][32]
        // flat u32 index -> consecutive per-wave LDS writes (conflict-free)
#pragma unroll
        for (int k = 0; k < 14; ++k) {
            const int mat = k / 7;
            const int within = (k % 7) * 256 + tid;      // n*16 + dp
            const int n  = within >> 4;
            const int dp = within & 15;
            const bool v = (n < H_);
            const int fi = mat * 3200 + (2 * dp) * H_ + (v ? n : 0);
            float x0 = v ? stgWf[fi]      : 0.f;
            float x1 = v ? stgWf[fi + H_] : 0.f;
            unsigned short h0 = bfhi(x0), h1 = bfhi(x1);
            unsigned short l0 = bfhi(x0 - bfback(h0)), l1 = bfhi(x1 - bfback(h1));
            wTu[(mat * 2 + 0) * 1792 + within] = (unsigned)h0 | ((unsigned)h1 << 16);
            wTu[(mat * 2 + 1) * 1792 + within] = (unsigned)l0 | ((unsigned)l1 << 16);
        }

        __syncthreads();   // (B) wT ready; stgWf free

        if (ch + 1 < NC) { stageH(cb ^ 1, d0 + DC); stageW(d0 + DC); }

        // A fragments: read fp32 h LDS (swizzled slots), split to bf16 hi/lo
        bf16x8 Ahi[6], Alo[6];
#pragma unroll
        for (int a = 0; a < 6; ++a) {
            const int row = (w + 4 * a) * 16 + ln;
            const int swR = (row ^ (row >> 3)) & 7;
            const float4* rp = csH + row * 8;
            float4 x0 = rp[(2 * lg) ^ swR];
            float4 x1 = rp[(2 * lg + 1) ^ swR];
#pragma unroll
            for (int j = 0; j < 4; ++j) {
                float v0 = ((const float*)&x0)[j];
                unsigned short hh = bfhi(v0);
                Ahi[a][j] = (short)hh;
                Alo[a][j] = (short)bfhi(v0 - bfback(hh));
            }
#pragma unroll
            for (int j = 0; j < 4; ++j) {
                float v1 = ((const float*)&x1)[j];
                unsigned short hh = bfhi(v1);
                Ahi[a][4 + j] = (short)hh;
                Alo[a][4 + j] = (short)bfhi(v1 - bfback(hh));
            }
        }

        // MFMA: per N-tile load 4 B-frags, 3 split-MFMAs per (a, nt)
#pragma unroll
        for (int nt = 0; nt < 7; ++nt) {
            bf16x8 B[2][2];
#pragma unroll
            for (int mat = 0; mat < 2; ++mat)
#pragma unroll
                for (int hl = 0; hl < 2; ++hl)
                    B[mat][hl] = *(const bf16x8*)&wT[(mat * 2 + hl) * 3584 +
                                                     (nt * 16 + ln) * 32 + lg * 8];
#pragma unroll
            for (int a = 0; a < 6; ++a) {
                const int mm = (a < 2) ? 0 : 1;
                acc[a][nt] = __builtin_amdgcn_mfma_f32_16x16x32_bf16(Ahi[a], B[mm][0], acc[a][nt], 0, 0, 0);
                acc[a][nt] = __builtin_amdgcn_mfma_f32_16x16x32_bf16(Ahi[a], B[mm][1], acc[a][nt], 0, 0, 0);
                acc[a][nt] = __builtin_amdgcn_mfma_f32_16x16x32_bf16(Alo[a], B[mm][0], acc[a][nt], 0, 0, 0);
            }
        }
    }

    // ---- epilogue: bias + relu-combine + out-layer, in registers ----
    float sB7[7], dB7[7], woA[7], woB[7];
    bool valn[7];
#pragma unroll
    for (int nt = 0; nt < 7; ++nt) {
        int n = nt * 16 + ln;
        valn[nt] = (n < H_);
        int nc = valn[nt] ? n : (H_ - 1);
        sB7[nt] = srcB[t * H_ + nc];
        dB7[nt] = dstB[t * H_ + nc];
        float2 wo = *(const float2*)(outW + (size_t)t * H_ * C_ + nc * C_);
        woA[nt] = wo.x; woB[nt] = wo.y;
    }

    float pp[16], nn[16];   // idx = a*8 + reg*2 + c
#pragma unroll
    for (int i = 0; i < 16; ++i) { pp[i] = 0.f; nn[i] = 0.f; }
#pragma unroll
    for (int nt = 0; nt < 7; ++nt)
#pragma unroll
        for (int a = 0; a < 2; ++a)
#pragma unroll
            for (int reg = 0; reg < 4; ++reg) {
                float sv = acc[a][nt][reg] + sB7[nt] + dB7[nt];
                float pe = fmaxf(acc[a + 2][nt][reg] + sv, 0.f);
                float ne = fmaxf(acc[a + 4][nt][reg] + sv, 0.f);
                pe = valn[nt] ? pe : 0.f;
                ne = valn[nt] ? ne : 0.f;
                const int ix = a * 8 + reg * 2;
                pp[ix]     = fmaf(pe, woA[nt], pp[ix]);
                pp[ix + 1] = fmaf(pe, woB[nt], pp[ix + 1]);
                nn[ix]     = fmaf(ne, woA[nt], nn[ix]);
                nn[ix + 1] = fmaf(ne, woB[nt], nn[ix + 1]);
            }

    float totP = fold16(pp, ln);
    float totN = fold16(nn, ln);
    {
        const int c   = ln & 1;
        const int reg = (ln >> 1) & 3;
        const int aa  = (ln >> 3) & 1;
        const int e   = (w + 4 * aa) * 16 + lg * 4 + reg;
        if (i0 + e < cnt) {
            float ob = outB[t * C_ + c];
            size_t pidx = (size_t)(base + i0 + e) * C_ + c;
            out[pidx] = totP + ob;
            out[(size_t)C_ * E + pidx] = totN + ob;
        }
    }
}

// ---------------------------------------------------------------------------
extern "C" void kernel_launch(void* const* d_in, const int* in_sizes, int n_in,
                              void* d_out, int out_size, void* d_ws, size_t ws_size,
                              hipStream_t stream) {
    (void)n_in; (void)out_size; (void)ws_size;
    const float* h    = (const float*)d_in[0];
    const float* srcW = (const float*)d_in[1];
    const float* srcB = (const float*)d_in[2];
    const float* dstW = (const float*)d_in[3];
    const float* dstB = (const float*)d_in[4];
    const float* outW = (const float*)d_in[5];
    const float* outB = (const float*)d_in[6];
    const int*   et   = (const int*)d_in[7];
    const int E = in_sizes[7];

    float* out = (float*)d_out;
    int* ws = (int*)d_ws;
    int* typeBase  = ws;
    int* typeCount = ws + 8;
    int* tileBase  = ws + 16;
    int* hist      = ws + WS_HIST;
    int* sorted_e  = ws + WS_SORTED;

    const int seg = (E + SB - 1) / SB;
    k_hist<<<SB, STH, 0, stream>>>(et, E, seg, hist);
    k_scan<<<1, SB, 0, stream>>>(hist, typeBase, typeCount, tileBase);
    k_scatter<<<SB, STH, 0, stream>>>(et, E, seg, hist, sorted_e);

    const int maxTiles = (E + TE - 1) / TE + T_;
    k_main<<<maxTiles, NTH, 0, stream>>>(h, srcW, srcB, dstW, dstB, outW, outB,
                                         sorted_e, typeBase, typeCount, tileBase,
                                         out, E);
}

// Round 8
// 1050.196 us; speedup vs baseline: 3.3808x; 1.0012x over previous
//
#include <hip/hip_runtime.h>

// Problem constants (from reference): T=8, D=512, H=100, C=2, NEG=1
constexpr int D_ = 512;
constexpr int H_ = 100;
constexpr int C_ = 2;
constexpr int T_ = 8;

constexpr int TE  = 128;        // edges per tile
constexpr int DC  = 32;         // D-chunk (floats) = one 128B line per row = one MFMA K
constexpr int NC  = D_ / DC;    // 16 chunks
constexpr int NTH = 256;        // 4 waves -> traffic-safe regime (R1/R6/R7-proven)
constexpr int GRID_MAIN = 256;  // persistent: one block per CU
constexpr int SB  = 128;        // sort segments / blocks
constexpr int STH = 256;        // threads per sort block

// ws ints: [0:8) typeBase | [8:16) typeCount | [16:25) tileBase | [26] tile ctr
//          [32:32+SB*8) hist/blockBase | [1056:1056+E) sorted_e
constexpr int WS_CTR  = 26;
constexpr int WS_HIST = 32;
constexpr int WS_SORTED = 32 + SB * T_;   // 1056

typedef __attribute__((ext_vector_type(8))) short bf16x8;
typedef __attribute__((ext_vector_type(4))) float f32x4;

__device__ __forceinline__ unsigned short bfhi(float x) {
    return (unsigned short)(__builtin_bit_cast(unsigned int, x) >> 16);
}
__device__ __forceinline__ float bfback(unsigned short u) {
    return __builtin_bit_cast(float, (unsigned int)u << 16);
}

// ---------------------------------------------------------------------------
// K1: per-segment histogram. SB blocks x STH threads.
// ---------------------------------------------------------------------------
__global__ __launch_bounds__(STH) void k_hist(const int* __restrict__ et, int E, int seg,
                                              int* __restrict__ hist) {
    __shared__ int hb[T_];
    const int b = blockIdx.x, tid = threadIdx.x;
    if (tid < T_) hb[tid] = 0;
    __syncthreads();
    const int segLo = b * seg;
    const int segHi = min(E, segLo + seg);
    const int per = (seg + STH - 1) / STH;
    const int lo = segLo + tid * per;
    const int hi = min(segHi, lo + per);
    int c[T_];
#pragma unroll
    for (int j = 0; j < T_; ++j) c[j] = 0;
    for (int i = lo; i < hi; ++i) {
        int ty = et[i];
#pragma unroll
        for (int j = 0; j < T_; ++j) c[j] += (ty == j) ? 1 : 0;
    }
#pragma unroll
    for (int j = 0; j < T_; ++j)
        if (c[j]) atomicAdd(&hb[j], c[j]);
    __syncthreads();
    if (tid < T_) hist[b * T_ + tid] = hb[tid];
}

// ---------------------------------------------------------------------------
// K2: scan over SB segment histograms (one block of SB threads).
// Also initializes the persistent-tile atomic counter.
// ---------------------------------------------------------------------------
__global__ __launch_bounds__(SB) void k_scan(int* __restrict__ hist,
                                             int* __restrict__ typeBase,
                                             int* __restrict__ typeCount,
                                             int* __restrict__ tileBase,
                                             int* __restrict__ ctr, int grid0) {
    __shared__ int sc[SB][T_ + 1];
    __shared__ int sbase[T_];
    const int tid = threadIdx.x;
#pragma unroll
    for (int j = 0; j < T_; ++j) sc[tid][j] = hist[tid * T_ + j];
    __syncthreads();
    for (int ofs = 1; ofs < SB; ofs <<= 1) {
        int v[T_];
        if (tid >= ofs) {
#pragma unroll
            for (int j = 0; j < T_; ++j) v[j] = sc[tid - ofs][j];
        }
        __syncthreads();
        if (tid >= ofs) {
#pragma unroll
            for (int j = 0; j < T_; ++j) sc[tid][j] += v[j];
        }
        __syncthreads();
    }
    if (tid == 0) {
        int b = 0, tb = 0;
#pragma unroll
        for (int j = 0; j < T_; ++j) {
            int cntj = sc[SB - 1][j];
            sbase[j] = b;
            typeBase[j] = b;
            typeCount[j] = cntj;
            tileBase[j] = tb;
            b += cntj;
            tb += (cntj + TE - 1) / TE;
        }
        tileBase[T_] = tb;
        ctr[0] = grid0;          // persistent blocks steal tiles >= grid0
    }
    __syncthreads();
#pragma unroll
    for (int j = 0; j < T_; ++j)
        hist[tid * T_ + j] = sbase[j] + (tid ? sc[tid - 1][j] : 0);
}

// ---------------------------------------------------------------------------
// K3: stable scatter. SB blocks x STH threads, same segmentation as K1.
// ---------------------------------------------------------------------------
__global__ __launch_bounds__(STH) void k_scatter(const int* __restrict__ et, int E, int seg,
                                                 const int* __restrict__ blockBase,
                                                 int* __restrict__ sorted_e) {
    __shared__ int sc[STH][T_ + 1];
    const int b = blockIdx.x, tid = threadIdx.x;
    const int segLo = b * seg;
    const int segHi = min(E, segLo + seg);
    const int per = (seg + STH - 1) / STH;
    const int lo = segLo + tid * per;
    const int hi = min(segHi, lo + per);
    int c[T_];
#pragma unroll
    for (int j = 0; j < T_; ++j) c[j] = 0;
    for (int i = lo; i < hi; ++i) {
        int ty = et[i];
#pragma unroll
        for (int j = 0; j < T_; ++j) c[j] += (ty == j) ? 1 : 0;
    }
#pragma unroll
    for (int j = 0; j < T_; ++j) sc[tid][j] = c[j];
    __syncthreads();
    for (int ofs = 1; ofs < STH; ofs <<= 1) {
        int v[T_];
        if (tid >= ofs) {
#pragma unroll
            for (int j = 0; j < T_; ++j) v[j] = sc[tid - ofs][j];
        }
        __syncthreads();
        if (tid >= ofs) {
#pragma unroll
            for (int j = 0; j < T_; ++j) sc[tid][j] += v[j];
        }
        __syncthreads();
    }
    int p[T_];
#pragma unroll
    for (int j = 0; j < T_; ++j)
        p[j] = blockBase[b * T_ + j] + (tid ? sc[tid - 1][j] : 0);
    for (int i = lo; i < hi; ++i) {
        int ty = et[i];
        int r = 0;
#pragma unroll
        for (int j = 0; j < T_; ++j) {
            if (ty == j) { r = p[j]; p[j] = r + 1; }
        }
        sorted_e[r] = i;
    }
}

// ---------------------------------------------------------------------------
// 16-lane butterfly fold (verified R7).
// ---------------------------------------------------------------------------
__device__ __forceinline__ float fold16(float (&v)[16], int ln) {
    float v8[8];
#pragma unroll
    for (int a = 0; a < 8; ++a) {
        float keep = (ln & 1) ? v[2 * a + 1] : v[2 * a];
        float send = (ln & 1) ? v[2 * a] : v[2 * a + 1];
        v8[a] = keep + __shfl_xor(send, 1);
    }
    float v4[4];
#pragma unroll
    for (int a = 0; a < 4; ++a) {
        float keep = (ln & 2) ? v8[2 * a + 1] : v8[2 * a];
        float send = (ln & 2) ? v8[2 * a] : v8[2 * a + 1];
        v4[a] = keep + __shfl_xor(send, 2);
    }
    float v2[2];
#pragma unroll
    for (int a = 0; a < 2; ++a) {
        float keep = (ln & 4) ? v4[2 * a + 1] : v4[2 * a];
        float send = (ln & 4) ? v4[2 * a] : v4[2 * a + 1];
        v2[a] = keep + __shfl_xor(send, 4);
    }
    float keep = (ln & 8) ? v2[1] : v2[0];
    float send = (ln & 8) ? v2[0] : v2[1];
    return keep + __shfl_xor(send, 8);
}

// ---------------------------------------------------------------------------
// Main fused kernel, v8 (structure = verified R7, three changes):
// (1) full-overlap chunk pipeline: W loads (global->reg, L2) issued first,
//     then gll stage(ch+1), then convert; lgkm-only barrier before MFMA so
//     gll(ch+1) spans the whole chunk (drained only at next full barrier).
// (2) wT layout [g][lg][slot'(n)][16B] with slot' = n ^ ((n>>3)&7):
//     MFMA B-reads conflict-free (consecutive 16B per 16-lane group).
// (3) persistent blocks (grid 256) + atomic tile stealing.
// ---------------------------------------------------------------------------
__global__ __launch_bounds__(NTH, 1) void k_main(
    const float* __restrict__ h,
    const float* __restrict__ srcW, const float* __restrict__ srcB,
    const float* __restrict__ dstW, const float* __restrict__ dstB,
    const float* __restrict__ outW, const float* __restrict__ outB,
    const int* __restrict__ sorted_e,
    const int* __restrict__ typeBase, const int* __restrict__ typeCount,
    const int* __restrict__ tileBase,
    int* __restrict__ ctr,
    float* __restrict__ out, int E)
{
    const int tid = threadIdx.x;
    const int w   = tid >> 6;          // wave 0..3
    const int l   = tid & 63;
    const int ln  = l & 15;            // tile row (A) / col (B,C)
    const int lg  = l >> 4;            // k-group 0..3

    __shared__ __align__(16) float4 stgH[2][3 * TE * (DC / 4)];   // 98304 B
    __shared__ __align__(16) unsigned wTu[4 * 4 * 112 * 4];       // 28672 B
    __shared__ int eIdx[TE];
    __shared__ int sNext;

    const int nT = tileBase[T_];
    const size_t mStride = (size_t)E * D_;
    float* const outH = out + (size_t)4 * E;

    // convert-item decomposition: item -> (mat, lg, n); 896 = 2*4*112 items.
    int cmat[4], clg[4], cn[4], cnld[4], cslot[4];
    bool cok[4];
#pragma unroll
    for (int it = 0; it < 4; ++it) {
        int item = it * 256 + tid;
        cok[it] = item < 896;
        int itc = cok[it] ? item : 0;
        cmat[it] = itc / 448;
        int rem  = itc % 448;
        clg[it]  = rem / 112;
        cn[it]   = rem % 112;
        cnld[it] = (cn[it] < H_) ? cn[it] : (H_ - 1);
        cslot[it] = cn[it] ^ ((cn[it] >> 3) & 7);
    }

    int tile = blockIdx.x;
    while (tile < nT) {
        int t = 0;
#pragma unroll
        for (int j = 1; j < T_; ++j) t += (tile >= tileBase[j]) ? 1 : 0;
        const int i0   = (tile - tileBase[t]) * TE;
        const int cnt  = typeCount[t];
        const int base = typeBase[t];

        if (tid < TE) {
            int p = i0 + tid;
            eIdx[tid] = sorted_e[base + (p < cnt ? p : i0)];
        }
        __syncthreads();   // eIdx visible

        // ---- per-tile h staging geometry (R6/R7-proven) ----
        const int r0 = tid >> 3, s8 = tid & 7;
        const float* rowSrc[4]; float* rowHS[4]; int slotLin[4]; bool gok[4];
#pragma unroll
        for (int rr4 = 0; rr4 < 4; ++rr4) {
            int rr = r0 + rr4 * 32;
            int sw = (rr ^ (rr >> 3)) & 7;
            int c4 = s8 ^ sw;
            int e  = eIdx[rr];
            rowSrc[rr4]  = h    + (size_t)e * D_ + (c4 << 2);
            rowHS[rr4]   = outH + (size_t)e * D_ + (s8 << 2);
            slotLin[rr4] = rr * 8 + c4;
            gok[rr4]     = (i0 + rr) < cnt;
        }

        const float* wsBase = srcW + (size_t)t * D_ * H_;
        const float* wdBase = dstW + (size_t)t * D_ * H_;

        auto stageH = [&](int buf, int d0c) {
            float4* dH = &stgH[buf][0];
#pragma unroll
            for (int m = 0; m < 3; ++m)
#pragma unroll
                for (int rr4 = 0; rr4 < 4; ++rr4)
                    __builtin_amdgcn_global_load_lds(
                        (const __attribute__((address_space(1))) void*)(rowSrc[rr4] + m * mStride + d0c),
                        (__attribute__((address_space(3))) void*)(dH + m * 1024 + rr4 * 256 + tid),
                        16, 0, 0);
        };

        f32x4 acc[6][7];
#pragma unroll
        for (int a = 0; a < 6; ++a)
#pragma unroll
            for (int nt = 0; nt < 7; ++nt) acc[a][nt] = (f32x4){0.f, 0.f, 0.f, 0.f};

        stageH(0, 0);

#pragma unroll 1
        for (int ch = 0; ch < NC; ++ch) {
            const int d0 = ch * DC;
            const int cb = ch & 1;

            __syncthreads();   // full: gll(ch) landed; all waves done chunk ch-1

            // (oldest vm ops) weight loads for this chunk, L2-resident, n-coalesced
            float wf[4][8];
#pragma unroll
            for (int it = 0; it < 4; ++it) {
                const float* wb = (cmat[it] ? wdBase : wsBase)
                                + (size_t)(d0 + clg[it] * 8) * H_ + cnld[it];
#pragma unroll
                for (int j = 0; j < 8; ++j) wf[it][j] = wb[(size_t)j * H_];
            }

            if (ch + 1 < NC) stageH(cb ^ 1, d0 + DC);   // in flight across whole chunk

            const float4* csH = &stgH[cb][0];

            // fused h_save: de-permuted readback, ascending full-line stores
#pragma unroll
            for (int m = 0; m < 2; ++m)
#pragma unroll
                for (int rr4 = 0; rr4 < 4; ++rr4) {
                    float4 v = csH[m * 1024 + slotLin[rr4]];
                    if (gok[rr4]) *(float4*)(rowHS[rr4] + m * mStride + d0) = v;
                }

            // convert: fp32 -> bf16 hi/lo, b128 writes into swizzled wT
#pragma unroll
            for (int it = 0; it < 4; ++it) {
                if (cok[it]) {
                    unsigned hu[4], lu[4];
#pragma unroll
                    for (int p = 0; p < 4; ++p) {
                        float x0 = wf[it][2 * p], x1 = wf[it][2 * p + 1];
                        unsigned short h0 = bfhi(x0), h1 = bfhi(x1);
                        unsigned short l0 = bfhi(x0 - bfback(h0));
                        unsigned short l1 = bfhi(x1 - bfback(h1));
                        hu[p] = (unsigned)h0 | ((unsigned)h1 << 16);
                        lu[p] = (unsigned)l0 | ((unsigned)l1 << 16);
                    }
                    int bHi = (((cmat[it] * 2 + 0) * 4 + clg[it]) * 112 + cslot[it]) * 4;
                    int bLo = (((cmat[it] * 2 + 1) * 4 + clg[it]) * 112 + cslot[it]) * 4;
                    *(uint4*)&wTu[bHi] = (uint4){hu[0], hu[1], hu[2], hu[3]};
                    *(uint4*)&wTu[bLo] = (uint4){lu[0], lu[1], lu[2], lu[3]};
                }
            }

            // lgkm-only barrier: wT ready; gll(ch+1) stays in flight
            asm volatile("s_waitcnt lgkmcnt(0)\n\ts_barrier" ::: "memory");
            __builtin_amdgcn_sched_barrier(0);

            // A fragments: read fp32 h LDS (swizzled slots), split to bf16 hi/lo
            bf16x8 Ahi[6], Alo[6];
#pragma unroll
            for (int a = 0; a < 6; ++a) {
                const int row = (w + 4 * a) * 16 + ln;
                const int swR = (row ^ (row >> 3)) & 7;
                const float4* rp = csH + row * 8;
                float4 x0 = rp[(2 * lg) ^ swR];
                float4 x1 = rp[(2 * lg + 1) ^ swR];
#pragma unroll
                for (int j = 0; j < 4; ++j) {
                    float v0 = ((const float*)&x0)[j];
                    unsigned short hh = bfhi(v0);
                    Ahi[a][j] = (short)hh;
                    Alo[a][j] = (short)bfhi(v0 - bfback(hh));
                }
#pragma unroll
                for (int j = 0; j < 4; ++j) {
                    float v1 = ((const float*)&x1)[j];
                    unsigned short hh = bfhi(v1);
                    Ahi[a][4 + j] = (short)hh;
                    Alo[a][4 + j] = (short)bfhi(v1 - bfback(hh));
                }
            }

            // MFMA: B-frags conflict-free (consecutive 16B per 16-lane group)
#pragma unroll
            for (int nt = 0; nt < 7; ++nt) {
                const int n = nt * 16 + ln;
                const int slotP = n ^ ((n >> 3) & 7);
                bf16x8 B[2][2];
#pragma unroll
                for (int mat = 0; mat < 2; ++mat)
#pragma unroll
                    for (int hl = 0; hl < 2; ++hl)
                        B[mat][hl] = *(const bf16x8*)&wTu[(((mat * 2 + hl) * 4 + lg) * 112 + slotP) * 4];
#pragma unroll
                for (int a = 0; a < 6; ++a) {
                    const int mm = (a < 2) ? 0 : 1;
                    acc[a][nt] = __builtin_amdgcn_mfma_f32_16x16x32_bf16(Ahi[a], B[mm][0], acc[a][nt], 0, 0, 0);
                    acc[a][nt] = __builtin_amdgcn_mfma_f32_16x16x32_bf16(Ahi[a], B[mm][1], acc[a][nt], 0, 0, 0);
                    acc[a][nt] = __builtin_amdgcn_mfma_f32_16x16x32_bf16(Alo[a], B[mm][0], acc[a][nt], 0, 0, 0);
                }
            }
        }

        // ---- epilogue: bias + relu-combine + out-layer (verified R7) ----
        float sB7[7], dB7[7], woA[7], woB[7];
        bool valn[7];
#pragma unroll
        for (int nt = 0; nt < 7; ++nt) {
            int n = nt * 16 + ln;
            valn[nt] = (n < H_);
            int nc = valn[nt] ? n : (H_ - 1);
            sB7[nt] = srcB[t * H_ + nc];
            dB7[nt] = dstB[t * H_ + nc];
            float2 wo = *(const float2*)(outW + (size_t)t * H_ * C_ + nc * C_);
            woA[nt] = wo.x; woB[nt] = wo.y;
        }

        float pp[16], nn[16];
#pragma unroll
        for (int i = 0; i < 16; ++i) { pp[i] = 0.f; nn[i] = 0.f; }
#pragma unroll
        for (int nt = 0; nt < 7; ++nt)
#pragma unroll
            for (int a = 0; a < 2; ++a)
#pragma unroll
                for (int reg = 0; reg < 4; ++reg) {
                    float sv = acc[a][nt][reg] + sB7[nt] + dB7[nt];
                    float pe = fmaxf(acc[a + 2][nt][reg] + sv, 0.f);
                    float ne = fmaxf(acc[a + 4][nt][reg] + sv, 0.f);
                    pe = valn[nt] ? pe : 0.f;
                    ne = valn[nt] ? ne : 0.f;
                    const int ix = a * 8 + reg * 2;
                    pp[ix]     = fmaf(pe, woA[nt], pp[ix]);
                    pp[ix + 1] = fmaf(pe, woB[nt], pp[ix + 1]);
                    nn[ix]     = fmaf(ne, woA[nt], nn[ix]);
                    nn[ix + 1] = fmaf(ne, woB[nt], nn[ix + 1]);
                }

        float totP = fold16(pp, ln);
        float totN = fold16(nn, ln);
        {
            const int c   = ln & 1;
            const int reg = (ln >> 1) & 3;
            const int aa  = (ln >> 3) & 1;
            const int e   = (w + 4 * aa) * 16 + lg * 4 + reg;
            if (i0 + e < cnt) {
                float ob = outB[t * C_ + c];
                size_t pidx = (size_t)(base + i0 + e) * C_ + c;
                out[pidx] = totP + ob;
                out[(size_t)C_ * E + pidx] = totN + ob;
            }
        }

        // ---- steal next tile ----
        __syncthreads();                 // all waves done with stgH/wT/eIdx
        if (tid == 0) sNext = atomicAdd(ctr, 1);
        __syncthreads();
        tile = sNext;
    }
}

// ---------------------------------------------------------------------------
extern "C" void kernel_launch(void* const* d_in, const int* in_sizes, int n_in,
                              void* d_out, int out_size, void* d_ws, size_t ws_size,
                              hipStream_t stream) {
    (void)n_in; (void)out_size; (void)ws_size;
    const float* h    = (const float*)d_in[0];
    const float* srcW = (const float*)d_in[1];
    const float* srcB = (const float*)d_in[2];
    const float* dstW = (const float*)d_in[3];
    const float* dstB = (const float*)d_in[4];
    const float* outW = (const float*)d_in[5];
    const float* outB = (const float*)d_in[6];
    const int*   et   = (const int*)d_in[7];
    const int E = in_sizes[7];

    float* out = (float*)d_out;
    int* ws = (int*)d_ws;
    int* typeBase  = ws;
    int* typeCount = ws + 8;
    int* tileBase  = ws + 16;
    int* ctr       = ws + WS_CTR;
    int* hist      = ws + WS_HIST;
    int* sorted_e  = ws + WS_SORTED;

    const int seg = (E + SB - 1) / SB;
    k_hist<<<SB, STH, 0, stream>>>(et, E, seg, hist);
    k_scan<<<1, SB, 0, stream>>>(hist, typeBase, typeCount, tileBase, ctr, GRID_MAIN);
    k_scatter<<<SB, STH, 0, stream>>>(et, E, seg, hist, sorted_e);

    k_main<<<GRID_MAIN, NTH, 0, stream>>>(h, srcW, srcB, dstW, dstB, outW, outB,
                                          sorted_e, typeBase, typeCount, tileBase,
                                          ctr, out, E);
}